// Round 5
// baseline (420.038 us; speedup 1.0000x reference)
//
#include <hip/hip_runtime.h>
#include <hip/hip_bf16.h>
#include <cstdint>
#include <cstddef>

typedef __bf16 bf16;
typedef __bf16 bf16x4 __attribute__((ext_vector_type(4)));
typedef __bf16 bf16x8 __attribute__((ext_vector_type(8)));
typedef float f32x4 __attribute__((ext_vector_type(4)));
typedef float f32x16 __attribute__((ext_vector_type(16)));

#define MFMA16(a, b, c) __builtin_amdgcn_mfma_f32_16x16x32_bf16((a), (b), (c), 0, 0, 0)
#define MFMA32(a, b, c) __builtin_amdgcn_mfma_f32_32x32x16_bf16((a), (b), (c), 0, 0, 0)
#define GLD16(g, l) __builtin_amdgcn_global_load_lds( \
    (const __attribute__((address_space(1))) void*)(g), \
    (__attribute__((address_space(3))) void*)(l), 16, 0, 0)

constexpr int Bsz = 4, SX = 2048, SC = 2048, Dm = 512, H = 8, DK = 64;
constexpr float L2E = 1.4426950408889634f;

// ---------------------------------------------------------------------------
// cvt kernels
// ---------------------------------------------------------------------------
__global__ __launch_bounds__(256) void cvt_weights(
    const float* __restrict__ Wq, const float* __restrict__ Wk,
    const float* __restrict__ Wv, const float* __restrict__ Wo,
    bf16* __restrict__ out)
{
    int i = (blockIdx.x * 256 + threadIdx.x) * 8;   // 0 .. 4*262144-1
    int w = i >> 18;
    int off = i & 262143;
    const float* src = (w == 0) ? Wq : (w == 1) ? Wk : (w == 2) ? Wv : Wo;
    float4 v0 = *(const float4*)(src + off);
    float4 v1 = *(const float4*)(src + off + 4);
    bf16x8 o = { (bf16)v0.x, (bf16)v0.y, (bf16)v0.z, (bf16)v0.w,
                 (bf16)v1.x, (bf16)v1.y, (bf16)v1.z, (bf16)v1.w };
    *(bf16x8*)(out + i) = o;
}

__global__ __launch_bounds__(256) void cvt_xc(
    const float* __restrict__ x, const float* __restrict__ c,
    bf16* __restrict__ out)
{
    int i = (blockIdx.x * 256 + threadIdx.x) * 8;   // 0 .. 8M-1
    const float* src = (i < 4194304) ? x : c;
    int off = i & 4194303;
    float4 v0 = *(const float4*)(src + off);
    float4 v1 = *(const float4*)(src + off + 4);
    bf16x8 o = { (bf16)v0.x, (bf16)v0.y, (bf16)v0.z, (bf16)v0.w,
                 (bf16)v1.x, (bf16)v1.y, (bf16)v1.z, (bf16)v1.w };
    *(bf16x8*)(out + i) = o;
}

// rel_table (4095 x 8) -> relT (8 x 4095), pre-scaled by log2(e)
__global__ __launch_bounds__(256) void cvt_rel(
    const float* __restrict__ rel, float* __restrict__ relT)
{
    int h = blockIdx.y;
    int i = blockIdx.x * 256 + threadIdx.x;
    if (i < SX + SC - 1) relT[h * (SX + SC - 1) + i] = rel[i * H + h] * L2E;
}

// ---------------------------------------------------------------------------
// proj_gemm v2: Y = A @ W^T + bias.  A bf16 (M x 512), W bf16 (N x 512).
// Tile 128(M) x 64(N), BK=64, 256 thr = 4 waves, wave tile 64x32 (4x2 MFMA16).
// grid (N/64, M/128)  [n-major so m-tile reuse is concurrent]
// global_load_lds staging with PER-WAVE LDS bases (wave-uniform-base rule!),
// XOR chunk swizzle: LDS[row][c] = glb[row][c ^ (row&7)].
// MODE 0: Y bf16 std [(bh)*2048 + s]*64 + dk                          (Q)
// MODE 3: Y bf16 K-frag ((((bh*64+key/32)*4+ks)*2+l5)*32+key%32)*8+j  (K)
// MODE 4: Y bf16 V-frag (((((bh*32+key/64)*4+ks)*2+ng)*2+l5)*32+dk%32)*8+j
// MODE 2: Y fp32 m*512 + n                                            (out)
// ---------------------------------------------------------------------------
template <int MODE>
__global__ __launch_bounds__(256, 2) void proj_gemm(
    const bf16* __restrict__ A, const bf16* __restrict__ W,
    const float* __restrict__ bias, void* __restrict__ Yv)
{
    __shared__ alignas(16) bf16 As[128 * 64];
    __shared__ alignas(16) bf16 Bs[64 * 64];

    const int t = threadIdx.x;
    const int n0 = blockIdx.x * 64;
    const int m0 = blockIdx.y * 128;
    const int wid = t >> 6, lane = t & 63, lr = lane & 15, lq = lane >> 4;
    const int wm = (wid & 1) * 64, wn = (wid >> 1) * 32;

    const int rl = lane >> 3;             // 0..7 row within 8-row staging group
    const int ch = (lane & 7) ^ rl;       // xor-swizzled global 16B chunk

    f32x4 acc[4][2];
#pragma unroll
    for (int i = 0; i < 4; i++)
#pragma unroll
        for (int j = 0; j < 2; j++) acc[i][j] = f32x4{0.f, 0.f, 0.f, 0.f};

    for (int k0 = 0; k0 < Dm; k0 += 64) {
        // wave `wid` stages A-rows [wid*32, wid*32+32) and B-rows [wid*16, wid*16+16)
        const bf16* ga = A + (size_t)(m0 + wid * 32 + rl) * Dm + k0 + ch * 8;
        const bf16* gb = W + (size_t)(n0 + wid * 16 + rl) * Dm + k0 + ch * 8;
#pragma unroll
        for (int g = 0; g < 4; g++)
            GLD16(ga + (size_t)g * 8 * Dm, &As[(wid * 32 + g * 8) * 64]);
#pragma unroll
        for (int g = 0; g < 2; g++)
            GLD16(gb + (size_t)g * 8 * Dm, &Bs[(wid * 16 + g * 8) * 64]);
        __syncthreads();
#pragma unroll
        for (int ks = 0; ks < 2; ks++) {
            bf16x8 af[4], bfr[2];
#pragma unroll
            for (int mt = 0; mt < 4; mt++)
                af[mt] = *(const bf16x8*)&As[(wm + mt * 16 + lr) * 64 + (((ks * 4 + lq) ^ (lr & 7)) * 8)];
#pragma unroll
            for (int nt = 0; nt < 2; nt++)
                bfr[nt] = *(const bf16x8*)&Bs[(wn + nt * 16 + lr) * 64 + (((ks * 4 + lq) ^ (lr & 7)) * 8)];
#pragma unroll
            for (int mt = 0; mt < 4; mt++)
#pragma unroll
                for (int nt = 0; nt < 2; nt++)
                    acc[mt][nt] = MFMA16(af[mt], bfr[nt], acc[mt][nt]);
        }
        __syncthreads();
    }

    // epilogue
#pragma unroll
    for (int mt = 0; mt < 4; mt++) {
#pragma unroll
        for (int nt = 0; nt < 2; nt++) {
#pragma unroll
            for (int r = 0; r < 4; r++) {
                int m = m0 + wm + mt * 16 + lq * 4 + r;   // b*2048 + s
                int n = n0 + wn + nt * 16 + lr;           // h*64 + dk
                float v = acc[mt][nt][r] + bias[n];
                int bh = (m >> 11) * 8 + (n >> 6);
                int key = m & 2047, dk = n & 63;
                if constexpr (MODE == 0) {
                    ((bf16*)Yv)[(size_t)(bh * 2048 + key) * 64 + dk] = (bf16)v;
                } else if constexpr (MODE == 3) {
                    int idx = ((((bh * 64 + (key >> 5)) * 4 + (dk >> 4)) * 2 + ((dk >> 3) & 1)) * 32
                               + (key & 31)) * 8 + (dk & 7);
                    ((bf16*)Yv)[idx] = (bf16)v;
                } else if constexpr (MODE == 4) {
                    int idx = (((((bh * 32 + (key >> 6)) * 4 + ((key >> 4) & 3)) * 2 + (dk >> 5)) * 2
                                + ((key >> 3) & 1)) * 32 + (dk & 31)) * 8 + (key & 7);
                    ((bf16*)Yv)[idx] = (bf16)v;
                } else {
                    ((float*)Yv)[(size_t)m * Dm + n] = v;
                }
            }
        }
    }
}

// ---------------------------------------------------------------------------
// attn v4: 2048 blocks x 192 thr (3 waves). XCD swizzle (id%8 -> same bh set).
// Wave w handles key-tiles {w, w+3, ...} of 32 tiles (64 keys each).
// K/V in fragment-major layout -> all loads are base + lane*16B (coalesced).
// P tile: per-wave LDS 32x64 bf16, XOR-swizzled (chunk ^= q&7) -> conflict-free.
// Barrier-free K-loop; 2 barriers at end for 3-way combine.
// ---------------------------------------------------------------------------
__global__ __launch_bounds__(192, 6) void attn_kernel(
    const bf16* __restrict__ Qm, const bf16* __restrict__ Kf,
    const bf16* __restrict__ Vf, const float* __restrict__ relT,
    bf16* __restrict__ Oa)
{
    const int id = blockIdx.x;
    const int xcd = id & 7, j = id >> 3;
    const int bh = xcd + 8 * (j & 3);
    const int q0 = (j >> 2) * 32;
    const int h = bh & 7, b = bh >> 3;
    const int t = threadIdx.x;
    const int wid = t >> 6, lane = t & 63;
    const int l31 = lane & 31, l5 = lane >> 5;

    __shared__ alignas(16) char sm[16768];
    bf16*  Ps   = (bf16*)(sm + wid * 4096);            // per-wave 32x64, swizzled
    float* Bsl  = (float*)(sm + 12288) + wid * 96;     // per-wave bias slice
    float* Obuf = (float*)sm;                          // combine overlay (2x64x32)
    float* Lbuf = (float*)(sm + 16384);                // 2x32 partial l + 32 final

    const bf16* Qb = Qm + (size_t)bh * SC * DK;
    const float* rT = relT + h * (SX + SC - 1);

    // Q B-fragments (n=q, k=dk), resident all kernel
    bf16x8 qf[4];
#pragma unroll
    for (int ks = 0; ks < 4; ks++)
        qf[ks] = *(const bf16x8*)&Qb[(size_t)(q0 + l31) * DK + ks * 16 + l5 * 8];

    f32x16 oacc[2];
#pragma unroll
    for (int ng = 0; ng < 2; ng++)
#pragma unroll
        for (int r = 0; r < 16; r++) oacc[ng][r] = 0.f;
    float lsum = 0.f;

    const float sc = 0.125f * L2E;
    const int swz = (l31 & 7) * 8;   // P chunk xor, in elems

#pragma unroll 1
    for (int tt = wid; tt < 32; tt += 3) {
        const int k0 = tt * 64;
        int i0 = q0 - k0 + 1984;
        Bsl[lane] = rT[i0 + lane];
        if (lane < 31) Bsl[64 + lane] = rT[i0 + 64 + lane];

        // S^T = K·Q^T per 32-key group; exp2; swizzled P->LDS
#pragma unroll
        for (int kg = 0; kg < 2; kg++) {
            const bf16* kb = Kf + ((size_t)(bh * 64 + (k0 >> 5) + kg) * 4) * 512 + lane * 8;
            f32x16 s;
#pragma unroll
            for (int r = 0; r < 16; r++) s[r] = 0.f;
#pragma unroll
            for (int ks = 0; ks < 4; ks++) {
                bf16x8 kf = *(const bf16x8*)(kb + ks * 512);
                s = MFMA32(kf, qf[ks], s);  // D[key][q], lane col = q
            }
#pragma unroll
            for (int r4 = 0; r4 < 4; r4++) {
                float p[4];
#pragma unroll
                for (int r0 = 0; r0 < 4; r0++) {
                    int n = r0 + 8 * r4 + 4 * l5;            // key_local (0..31)
                    int ib = 63 + l31 - (kg * 32 + n);
                    p[r0] = __builtin_amdgcn_exp2f(s[r4 * 4 + r0] * sc + Bsl[ib]);
                    lsum += p[r0];
                }
                bf16x4 pk = { (bf16)p[0], (bf16)p[1], (bf16)p[2], (bf16)p[3] };
                *(bf16x4*)&Ps[l31 * 64 + (((kg * 4 + r4) * 8) ^ swz) + l5 * 4] = pk;
            }
        }
        // O += P @ V   (same-wave LDS RAW; no barrier)
        bf16x8 pf[4];
#pragma unroll
        for (int ks = 0; ks < 4; ks++)
            pf[ks] = *(const bf16x8*)&Ps[l31 * 64 + (((2 * ks + l5) * 8) ^ swz)];
#pragma unroll
        for (int ng = 0; ng < 2; ng++) {
            const bf16* vb = Vf + ((size_t)((bh * 32 + (k0 >> 6)) * 4) * 2 + ng) * 512 + lane * 8;
#pragma unroll
            for (int ks = 0; ks < 4; ks++) {
                bf16x8 vf = *(const bf16x8*)(vb + ks * 1024);
                oacc[ng] = MFMA32(pf[ks], vf, oacc[ng]);  // D[q][dk], lane col = dk
            }
        }
    }

    // ---- 3-way combine ----
    lsum += __shfl_xor(lsum, 32, 64);
    __syncthreads();                      // all waves done with Ps/Bsl
    if (wid) {
        float* Op = Obuf + ((wid - 1) * 64 + lane) * 32;
#pragma unroll
        for (int ng = 0; ng < 2; ng++)
#pragma unroll
            for (int q = 0; q < 4; q++) {
                f32x4 v = { oacc[ng][q * 4 + 0], oacc[ng][q * 4 + 1],
                            oacc[ng][q * 4 + 2], oacc[ng][q * 4 + 3] };
                *(f32x4*)(Op + ng * 16 + q * 4) = v;
            }
        if (lane < 32) Lbuf[(wid - 1) * 32 + l31] = lsum;
    }
    __syncthreads();
    if (wid == 0) {
        lsum += Lbuf[l31] + Lbuf[32 + l31];
#pragma unroll
        for (int w2 = 0; w2 < 2; w2++) {
            const float* Op = Obuf + (w2 * 64 + lane) * 32;
#pragma unroll
            for (int ng = 0; ng < 2; ng++)
#pragma unroll
                for (int q = 0; q < 4; q++) {
                    f32x4 v = *(const f32x4*)(Op + ng * 16 + q * 4);
#pragma unroll
                    for (int r0 = 0; r0 < 4; r0++) oacc[ng][q * 4 + r0] += v[r0];
                }
        }
        float* Lfin = Lbuf + 64;
        if (lane < 32) Lfin[l31] = lsum;
        // normalize + store bf16 [b][q][h*64+dk]  (same-wave LDS RAW)
#pragma unroll
        for (int r4 = 0; r4 < 4; r4++) {
            float4 lv = *(const float4*)&Lfin[8 * r4 + 4 * l5];
            float rv[4] = { 1.f / lv.x, 1.f / lv.y, 1.f / lv.z, 1.f / lv.w };
#pragma unroll
            for (int ng = 0; ng < 2; ng++) {
#pragma unroll
                for (int r0 = 0; r0 < 4; r0++) {
                    int row = r0 + 8 * r4 + 4 * l5;
                    Oa[((size_t)(b * SX + q0 + row)) * Dm + h * 64 + ng * 32 + l31] =
                        (bf16)(oacc[ng][r4 * 4 + r0] * rv[r0]);
                }
            }
        }
    }
}

// ---------------------------------------------------------------------------
// Launch
// ---------------------------------------------------------------------------
extern "C" void kernel_launch(void* const* d_in, const int* in_sizes, int n_in,
                              void* d_out, int out_size, void* d_ws, size_t ws_size,
                              hipStream_t stream)
{
    (void)in_sizes; (void)n_in; (void)out_size; (void)ws_size;

    const float* x   = (const float*)d_in[0];
    const float* c   = (const float*)d_in[1];
    const float* Wq  = (const float*)d_in[2];
    const float* bq  = (const float*)d_in[3];
    const float* Wk  = (const float*)d_in[4];
    const float* bk  = (const float*)d_in[5];
    const float* Wv  = (const float*)d_in[6];
    const float* bv  = (const float*)d_in[7];
    const float* Wo  = (const float*)d_in[8];
    const float* bo  = (const float*)d_in[9];
    const float* rel = (const float*)d_in[10];

    char* ws = (char*)d_ws;
    // layout: Wbf 0..2MB | XCbf 2..18MB (dead after V) / Aw overlay 2..10MB
    //         Q 18..26 | Kf 26..34 | Vf 34..42 | relT 42MB+128KB
    bf16*  Wbf  = (bf16*)ws;
    bf16*  Xbf  = (bf16*)(ws + (2u << 20));
    bf16*  Cbf  = Xbf + 4194304;
    bf16*  Aw   = (bf16*)(ws + (2u << 20));      // overlays XCbf (dead by then)
    bf16*  Qw   = (bf16*)(ws + (18u << 20));
    bf16*  Kw   = (bf16*)(ws + (26u << 20));
    bf16*  Vw   = (bf16*)(ws + (34u << 20));
    float* relT = (float*)(ws + (42u << 20));

    cvt_weights<<<512, 256, 0, stream>>>(Wq, Wk, Wv, Wo, Wbf);
    cvt_xc<<<4096, 256, 0, stream>>>(x, c, Xbf);
    cvt_rel<<<dim3(16, 8), 256, 0, stream>>>(rel, relT);

    dim3 pg(8, 64);  // (N/64, M/128)
    proj_gemm<0><<<pg, 256, 0, stream>>>(Xbf, Wbf + 0 * 262144, bq, Qw);
    proj_gemm<3><<<pg, 256, 0, stream>>>(Cbf, Wbf + 1 * 262144, bk, Kw);
    proj_gemm<4><<<pg, 256, 0, stream>>>(Cbf, Wbf + 2 * 262144, bv, Vw);

    attn_kernel<<<2048, 192, 0, stream>>>(Qw, Kw, Vw, relT, Aw);

    proj_gemm<2><<<pg, 256, 0, stream>>>(Aw, Wbf + 3 * 262144, bo, d_out);
}